// Round 2
// baseline (406.733 us; speedup 1.0000x reference)
//
#include <hip/hip_runtime.h>
#include <stdint.h>

// Problem constants (B=4, S=2048, K=4096, N=4096 -> M = B*S = 8192)
#define MDIM 8192
#define NDIM 4096
#define KDIM 4096

// GEMM tiling: 256x256 tile, BK=128 (i8 -> 128B rows), 512 threads = 8 waves
// (2M x 4N), per-wave 128x64 output via 4x2 grid of mfma_i32_32x32x32_i8.
// Double-buffered LDS (128 KiB), 8-phase schedule. R2 change: front-loaded
// ds_reads (P1: 16, P2: 8, P3/P4: 0) with compiler-counted lgkm waits so the
// LDS burst overlaps the MFMA phases (the R1 structure serialized
// read_burst + MMA inside every phase -> 36% MfmaUtil). Stage slots moved to
// the read-free phases with a re-derived region ledger; counted vmcnt keeps
// 3-4 phases of load-latency hiding.
#define BM 256
#define BN 256
#define BK 128
#define NKT (KDIM / BK)   // 32 K-tiles; main loop does 2/iter

typedef __attribute__((ext_vector_type(4)))  int i32x4;
typedef __attribute__((ext_vector_type(16))) int i32x16;

#define AS1 __attribute__((address_space(1)))
#define AS3 __attribute__((address_space(3)))

__device__ __forceinline__ int clamp127(int v) {
    return v > 127 ? 127 : (v < -127 ? -127 : v);
}

// ---- x fp32 -> int8, per-row symmetric quant (row = 4096 elems) ----
__global__ __launch_bounds__(256) void quant_x(
        const float* __restrict__ x, const float* __restrict__ sw,
        int8_t* __restrict__ Aq, float* __restrict__ scales) {
    const int row = blockIdx.x;
    const int t   = threadIdx.x;
    const float4* px = (const float4*)(x + (size_t)row * KDIM);

    float4 v[4];
#pragma unroll
    for (int j = 0; j < 4; j++) v[j] = px[t + 256 * j];

    float a = 0.f;
#pragma unroll
    for (int j = 0; j < 4; j++) {
        a = fmaxf(a, fabsf(v[j].x)); a = fmaxf(a, fabsf(v[j].y));
        a = fmaxf(a, fabsf(v[j].z)); a = fmaxf(a, fabsf(v[j].w));
    }
#pragma unroll
    for (int off = 32; off >= 1; off >>= 1)
        a = fmaxf(a, __shfl_xor(a, off));
    __shared__ float red[4];
    if ((t & 63) == 0) red[t >> 6] = a;
    __syncthreads();
    const float amax = fmaxf(fmaxf(red[0], red[1]), fmaxf(red[2], red[3]));
    const float inv  = (amax > 0.f) ? (127.0f / amax) : 0.f;
    if (t == 0) scales[row] = (amax * (1.0f / 127.0f)) * (*sw);

    int* out32 = (int*)(Aq + (size_t)row * KDIM);
#pragma unroll
    for (int j = 0; j < 4; j++) {
        int b0 = clamp127(__float2int_rn(v[j].x * inv));
        int b1 = clamp127(__float2int_rn(v[j].y * inv));
        int b2 = clamp127(__float2int_rn(v[j].z * inv));
        int b3 = clamp127(__float2int_rn(v[j].w * inv));
        out32[t + 256 * j] = (b0 & 255) | ((b1 & 255) << 8) | ((b2 & 255) << 16) | ((b3 & 255) << 24);
    }
}

// ---- qw int32 -> int8 (exact; values already in [-128,127]) ----
__global__ __launch_bounds__(256) void cvt_w(const int* __restrict__ qw, int8_t* __restrict__ Bq) {
    const long i = (long)blockIdx.x * 256 + threadIdx.x;
    int4 a = ((const int4*)qw)[i];
    ((int*)Bq)[i] = (a.x & 255) | ((a.y & 255) << 8) | ((a.z & 255) << 16) | ((a.w & 255) << 24);
}

// ======================= 256x256 8-phase i8 GEMM (v2) =======================
//
// LDS: [256 rows][128 B]/tile, phys_chunk = logical_chunk ^ (row & 7); linear
// global_load_lds dest + inverse-swizzled global source (rule #21).
//
// Read plan per tile (front-loaded; compiler emits counted lgkmcnt per use):
//   P1: read A.mh0 -> aF0 (8), B.n0+n1 -> bF (8); MMA0(0) waits first 12.
//   P2: read A.mh1 -> aF1 (8); MMA0(1) waits bF1 only (aF1 flows under it).
//   P3: pure MFMA  MMA1(1)   (aF1 drained by its own use).
//   P4: pure MFMA  MMA1(0).
// Region-safety ledger (all-waves read completion is guaranteed by the use-
// wait inside phase p + p's closing barrier):
//   buf.B regions free from P3 (last use MMA0(1)@P2); buf.A free from P4
//   (last use MMA1(1)@P3... aF1 read@P2, used@P3) -> A free from P4+.
// Stage slots: P3: t2.Bh0 | P4: t2.Bh1, vmcnt(4) | P5: t2.Ah0+Ah1 |
//   P7: t3.Bh0+Bh1 | P8: t3.Ah0+Ah1, vmcnt(8).
// vmcnt ledger (2 loads/STAGE):
//   @P4: outstanding = t1.B(prevP7,4) + t1.A(prevP8,4) + t2.B(P3/P4,4) = 12;
//        vmcnt(4) drains t1 fully (youngest staged 4 phases earlier) before
//        buf1 is read at P5.
//   @P8: outstanding = t2.A(P5,4) + t3.B(P7,4) + t3.A(P8,4) = 12;
//        vmcnt(8) drains t2.A (3 phases) before buf0 is read at next-P1.

#define BAR()    do { asm volatile("" ::: "memory"); __builtin_amdgcn_s_barrier(); asm volatile("" ::: "memory"); } while (0)
#define WAITV(n) asm volatile("s_waitcnt vmcnt(" #n ")" ::: "memory")

#define STAGE_A(buf, h, kt) do { \
    __builtin_amdgcn_global_load_lds((AS1 const void*)(gA + (size_t)((h) * 128) * KDIM + (kt) * 128), \
        (AS3 void*)(sA + (buf) * 32768 + (h) * 16384 + sdst), 16, 0, 0); \
    __builtin_amdgcn_global_load_lds((AS1 const void*)(gA + (size_t)((h) * 128 + 64) * KDIM + (kt) * 128), \
        (AS3 void*)(sA + (buf) * 32768 + (h) * 16384 + 8192 + sdst), 16, 0, 0); \
} while (0)

#define STAGE_B(buf, h, kt) do { \
    __builtin_amdgcn_global_load_lds((AS1 const void*)(gB + (size_t)((h) * 128) * KDIM + (kt) * 128), \
        (AS3 void*)(sB + (buf) * 32768 + (h) * 16384 + sdst), 16, 0, 0); \
    __builtin_amdgcn_global_load_lds((AS1 const void*)(gB + (size_t)((h) * 128 + 64) * KDIM + (kt) * 128), \
        (AS3 void*)(sB + (buf) * 32768 + (h) * 16384 + 8192 + sdst), 16, 0, 0); \
} while (0)

// A M-half 0 (rows wr*128 + 0..63) -> aF0 ; M-half 1 (rows +64..127) -> aF1
#define READ_A0(buf) do { \
    _Pragma("unroll") for (int q = 0; q < 2; ++q) \
    _Pragma("unroll") for (int ks = 0; ks < 4; ++ks) \
        aF0[q][ks] = *(const i32x4*)(sA + (buf) * 32768 + rbA + q * 4096 + co[ks]); \
} while (0)

#define READ_A1(buf) do { \
    _Pragma("unroll") for (int q = 0; q < 2; ++q) \
    _Pragma("unroll") for (int ks = 0; ks < 4; ++ks) \
        aF1[q][ks] = *(const i32x4*)(sA + (buf) * 32768 + rbA + (2 + q) * 4096 + co[ks]); \
} while (0)

#define READ_Bb(buf) do { \
    _Pragma("unroll") for (int ni = 0; ni < 2; ++ni) \
    _Pragma("unroll") for (int ks = 0; ks < 4; ++ks) \
        bF[ni][ks] = *(const i32x4*)(sB + (buf) * 32768 + rbB + (ni) * 4096 + co[ks]); \
} while (0)

#define MMA0(ni) do { \
    __builtin_amdgcn_s_setprio(1); \
    _Pragma("unroll") for (int ks = 0; ks < 4; ++ks) { \
        acc[0][ni] = __builtin_amdgcn_mfma_i32_32x32x32_i8(aF0[0][ks], bF[ni][ks], acc[0][ni], 0, 0, 0); \
        acc[1][ni] = __builtin_amdgcn_mfma_i32_32x32x32_i8(aF0[1][ks], bF[ni][ks], acc[1][ni], 0, 0, 0); \
    } \
    __builtin_amdgcn_s_setprio(0); \
} while (0)

#define MMA1(ni) do { \
    __builtin_amdgcn_s_setprio(1); \
    _Pragma("unroll") for (int ks = 0; ks < 4; ++ks) { \
        acc[2][ni] = __builtin_amdgcn_mfma_i32_32x32x32_i8(aF1[0][ks], bF[ni][ks], acc[2][ni], 0, 0, 0); \
        acc[3][ni] = __builtin_amdgcn_mfma_i32_32x32x32_i8(aF1[1][ks], bF[ni][ks], acc[3][ni], 0, 0, 0); \
    } \
    __builtin_amdgcn_s_setprio(0); \
} while (0)

__global__ __launch_bounds__(512, 2) void gemm_bt_i8(
        const int8_t* __restrict__ A,    // [M,K] int8
        const int8_t* __restrict__ Bm,   // [N,K] int8
        const float* __restrict__ scales,// [M] = s_m * sw
        const float* __restrict__ bias,  // [N]
        float* __restrict__ C)           // [M,N] fp32
{
    __shared__ __align__(16) int8_t sA[2 * BM * BK];  // 64 KiB
    __shared__ __align__(16) int8_t sB[2 * BN * BK];  // 64 KiB

    const int tid  = threadIdx.x;
    const int wave = tid >> 6;
    const int lane = tid & 63;
    const int wr   = wave >> 2;       // 0..1  (M half)
    const int wc   = wave & 3;        // 0..3  (N quarter)
    const int l32  = lane & 31;
    const int hi   = lane >> 5;

    // T1: XCD-aware swizzle over 512 wgs (32 m-tiles x 16 n-tiles); 512%8==0.
    const int orig = blockIdx.y * 16 + blockIdx.x;
    const int nu   = (orig & 7) * 64 + (orig >> 3);
    const int m0   = (nu >> 4) * BM;
    const int n0   = (nu & 15) * BN;

    // ---- staging addresses (linear LDS dest, inverse-swizzled global src) ----
    const int trow = tid >> 3;                 // dest row within 64-row block
    const int slog = (tid & 7) ^ (trow & 7);   // source logical chunk
    const int8_t* gA = A  + (size_t)(m0 + trow) * KDIM + slog * 16;
    const int8_t* gB = Bm + (size_t)(n0 + trow) * KDIM + slog * 16;
    const int sdst = tid * 16;

    // ---- fragment read addresses ----
    const int swz = l32 & 7;
    const int rbA = (wr * 128 + l32) * BK;
    const int rbB = (wc * 64  + l32) * BK;
    int co[4];
#pragma unroll
    for (int ks = 0; ks < 4; ++ks) co[ks] = ((((ks << 1) | hi) ^ swz) << 4);

    i32x16 acc[4][2];
#pragma unroll
    for (int mi = 0; mi < 4; ++mi)
#pragma unroll
        for (int ni = 0; ni < 2; ++ni)
#pragma unroll
            for (int r = 0; r < 16; ++r) acc[mi][ni][r] = 0;

    i32x4 aF0[2][4];  // M-half 0 fragments (live P1-P2)
    i32x4 aF1[2][4];  // M-half 1 fragments (live P2-P4)
    i32x4 bF[2][4];   // both ni (live P1-P4)

    // ---- prologue: t0 full + t1 full staged; drain t0, t1 (8 loads) in flight ----
    STAGE_B(0, 0, 0); STAGE_B(0, 1, 0);
    STAGE_A(0, 0, 0); STAGE_A(0, 1, 0);
    STAGE_B(1, 0, 1); STAGE_B(1, 1, 1);
    STAGE_A(1, 0, 1); STAGE_A(1, 1, 1);
    WAITV(8);          // t0 landed; t1 (8 loads) in flight
    BAR();

#pragma unroll 1
    for (int it = 0; it < NKT / 2 - 1; ++it) {     // 15 iterations, tiles 0..29
        const int t2 = 2 * it + 2, t3 = 2 * it + 3;
        // P1: all buf0 reads except A.mh1; MMA needs first 12 -> counted lgkm
        READ_A0(0); READ_Bb(0);                    BAR(); MMA0(0); BAR();
        // P2: A.mh1 reads flow under MMA0(1) (which only waits bF[1])
        READ_A1(0);                                BAR(); MMA0(1); BAR();
        // P3: pure MFMA; buf0.B free (bF drained by P2's use + barrier)
        STAGE_B(0, 0, t2);                         BAR(); MMA1(1); BAR();
        // P4: pure MFMA; drain t1 (staged prev P7/P8 -> 4-phase distance)
        STAGE_B(0, 1, t2); WAITV(4);               BAR(); MMA1(0); BAR();
        // P5: buf1 reads; buf0.A free (aF1 drained by P3's use + barrier)
        READ_A0(1); READ_Bb(1);
        STAGE_A(0, 0, t2); STAGE_A(0, 1, t2);      BAR(); MMA0(0); BAR();
        // P6
        READ_A1(1);                                BAR(); MMA0(1); BAR();
        // P7: buf1.B free from here
        STAGE_B(1, 0, t3); STAGE_B(1, 1, t3);      BAR(); MMA1(1); BAR();
        // P8: buf1.A free from here; drain t2 (youngest staged P5, 3 phases)
        STAGE_A(1, 0, t3); STAGE_A(1, 1, t3); WAITV(8); BAR(); MMA1(0); BAR();
    }

    // ---- tail: tiles 30 (buf0) and 31 (buf1); no more staging ----
    READ_A0(0); READ_Bb(0);                        BAR(); MMA0(0); BAR();
    READ_A1(0);                                    BAR(); MMA0(1); BAR();
                                                   BAR(); MMA1(1); BAR();
    WAITV(0);                                      BAR(); MMA1(0); BAR();
    READ_A0(1); READ_Bb(1);                        BAR(); MMA0(0); BAR();
    READ_A1(1);                                    BAR(); MMA0(1); BAR();
    MMA1(1);
    MMA1(0);

    // ---- epilogue ----
    // C/D 32x32 layout: col = l32, row = (r&3) + 8*(r>>2) + 4*hi  [m74/m101]
#pragma unroll
    for (int mi = 0; mi < 4; ++mi) {
        const int row_base = m0 + wr * 128 + mi * 32 + 4 * hi;
        float sc[16];
#pragma unroll
        for (int r = 0; r < 16; ++r)
            sc[r] = scales[row_base + (r & 3) + 8 * (r >> 2)];
#pragma unroll
        for (int ni = 0; ni < 2; ++ni) {
            const int col = n0 + wc * 64 + ni * 32 + l32;
            const float bc = bias[col];
#pragma unroll
            for (int r = 0; r < 16; ++r) {
                const int row = row_base + (r & 3) + 8 * (r >> 2);
                C[(size_t)row * NDIM + col] = (float)acc[mi][ni][r] * sc[r] + bc;
            }
        }
    }
}

// ---- correctness fallback if workspace is too small (not expected to run) ----
__global__ void gemm_naive_f32(const float* __restrict__ x, const int* __restrict__ qw,
                               const float* __restrict__ sw, const float* __restrict__ bias,
                               float* __restrict__ out) {
    size_t id = (size_t)blockIdx.x * blockDim.x + threadIdx.x;
    if (id >= (size_t)MDIM * NDIM) return;
    int m = (int)(id / NDIM);
    int n = (int)(id % NDIM);
    const float* xr = x + (size_t)m * KDIM;
    const int*   wr = qw + (size_t)n * KDIM;
    float acc = 0.f;
    for (int k = 0; k < KDIM; k++) acc += xr[k] * (float)wr[k];
    out[id] = acc * (*sw) + bias[n];
}

extern "C" void kernel_launch(void* const* d_in, const int* in_sizes, int n_in,
                              void* d_out, int out_size, void* d_ws, size_t ws_size,
                              hipStream_t stream) {
    const float* x    = (const float*)d_in[0];
    const int*   qw   = (const int*)d_in[1];
    const float* sw   = (const float*)d_in[2];
    const float* bias = (const float*)d_in[3];
    float* out = (float*)d_out;

    const size_t needA = (size_t)MDIM * KDIM;                  // 32 MiB int8
    const size_t needB = (size_t)NDIM * KDIM;                  // 16 MiB int8
    const size_t needS = (size_t)MDIM * sizeof(float);         // 32 KiB scales

    if (ws_size >= needA + needB + needS) {
        int8_t* Aq = (int8_t*)d_ws;
        int8_t* Bq = Aq + needA;
        float*  scales = (float*)(Bq + needB);

        quant_x<<<MDIM, 256, 0, stream>>>(x, sw, Aq, scales);
        const long nw4 = (long)NDIM * KDIM / 4;
        cvt_w<<<(int)(nw4 / 256), 256, 0, stream>>>(qw, Bq);

        dim3 grid(NDIM / BN, MDIM / BM);                       // (16, 32) = 512 blocks
        gemm_bt_i8<<<grid, 512, 0, stream>>>(Aq, Bq, scales, bias, out);
    } else {
        size_t total = (size_t)MDIM * NDIM;
        gemm_naive_f32<<<(total + 255) / 256, 256, 0, stream>>>(x, qw, sw, bias, out);
    }
}

// Round 4
// 405.667 us; speedup vs baseline: 1.0026x; 1.0026x over previous
//
#include <hip/hip_runtime.h>
#include <stdint.h>

// Problem constants (B=4, S=2048, K=4096, N=4096 -> M = B*S = 8192)
#define MDIM 8192
#define NDIM 4096
#define KDIM 4096

// GEMM tiling: 256x256 tile, BK=128, 512 threads = 8 waves (2M x 4N),
// per-wave 128x64 output. R3/R4: MFMA 32x32x32 -> 16x16x64 so the LDS
// fragment-read pattern is byte-isomorphic to the verified conflict-free
// m201 pattern (16-lane row-groups reading uniform-stride 16B chunk columns)
// with m201's exact st_16x32 swizzle (chunk ^= ((row>>2)&1)<<1). R0-R2 all
// measured 4.0 extra cyc per ds_read_b128 (structural conflict of the 32x32
// fragment pattern, invariant across swizzles) -> ~2600 of 5925 cyc/tile.
// R4 fix vs R3: removed duplicate t1.A staging at P1/P2 (leftover from the
// R1 plan; P8 already stages it) -> stage plan identical to R2.
#define BM 256
#define BN 256
#define BK 128
#define NKT (KDIM / BK)   // 32 K-tiles; main loop does 2/iter

typedef __attribute__((ext_vector_type(4)))  int i32x4;

#define AS1 __attribute__((address_space(1)))
#define AS3 __attribute__((address_space(3)))

__device__ __forceinline__ int clamp127(int v) {
    return v > 127 ? 127 : (v < -127 ? -127 : v);
}

// ---- x fp32 -> int8, per-row symmetric quant (row = 4096 elems) ----
__global__ __launch_bounds__(256) void quant_x(
        const float* __restrict__ x, const float* __restrict__ sw,
        int8_t* __restrict__ Aq, float* __restrict__ scales) {
    const int row = blockIdx.x;
    const int t   = threadIdx.x;
    const float4* px = (const float4*)(x + (size_t)row * KDIM);

    float4 v[4];
#pragma unroll
    for (int j = 0; j < 4; j++) v[j] = px[t + 256 * j];

    float a = 0.f;
#pragma unroll
    for (int j = 0; j < 4; j++) {
        a = fmaxf(a, fabsf(v[j].x)); a = fmaxf(a, fabsf(v[j].y));
        a = fmaxf(a, fabsf(v[j].z)); a = fmaxf(a, fabsf(v[j].w));
    }
#pragma unroll
    for (int off = 32; off >= 1; off >>= 1)
        a = fmaxf(a, __shfl_xor(a, off));
    __shared__ float red[4];
    if ((t & 63) == 0) red[t >> 6] = a;
    __syncthreads();
    const float amax = fmaxf(fmaxf(red[0], red[1]), fmaxf(red[2], red[3]));
    const float inv  = (amax > 0.f) ? (127.0f / amax) : 0.f;
    if (t == 0) scales[row] = (amax * (1.0f / 127.0f)) * (*sw);

    int* out32 = (int*)(Aq + (size_t)row * KDIM);
#pragma unroll
    for (int j = 0; j < 4; j++) {
        int b0 = clamp127(__float2int_rn(v[j].x * inv));
        int b1 = clamp127(__float2int_rn(v[j].y * inv));
        int b2 = clamp127(__float2int_rn(v[j].z * inv));
        int b3 = clamp127(__float2int_rn(v[j].w * inv));
        out32[t + 256 * j] = (b0 & 255) | ((b1 & 255) << 8) | ((b2 & 255) << 16) | ((b3 & 255) << 24);
    }
}

// ---- qw int32 -> int8 (exact; values already in [-128,127]) ----
__global__ __launch_bounds__(256) void cvt_w(const int* __restrict__ qw, int8_t* __restrict__ Bq) {
    const long i = (long)blockIdx.x * 256 + threadIdx.x;
    int4 a = ((const int4*)qw)[i];
    ((int*)Bq)[i] = (a.x & 255) | ((a.y & 255) << 8) | ((a.z & 255) << 16) | ((a.w & 255) << 24);
}

// ======================= 256x256 8-phase i8 GEMM (v4, 16x16x64) =======================
//
// LDS: [256 rows][128 B] per tile array. Swizzle (m201 st_16x32, byte-exact):
//   phys_chunk = logical_chunk ^ (((row>>2)&1)<<1)   (chunk = 16B unit, 8/row)
// Staging: linear global_load_lds dest + inverse-swizzled global source.
//
// 16x16x64 fragment: lane l holds row (l&15), k-bytes (l>>4)*16 + ks*64.
//   -> per 16-lane group: uniform 128-B stride, single chunk column (the
//      measured-conflict-free pattern). chunk offset = ks*64 + ((lg^f)<<4),
//      f = ((lr>>2)&1)<<1  (mi*16/ni*16 row bases preserve row bit 2).
// C/D layout (16x16, dtype-independent, m89/m91): col = l&15, row = (l>>4)*4+r.
//
// Phase plan per iteration (tiles T0=2i in buf0, T1=2i+1 in buf1):
//   P1: rd A.mh0(8) + B all(8) |              | MMA(mh0,nh0)
//   P2: rd A.mh1(8)            |              | MMA(mh0,nh1)
//   P3:                        | stage t2.Bh0 | MMA(mh1,nh1)
//   P4:                        | stage t2.Bh1, vmcnt(4) | MMA(mh1,nh0)
//   P5-P8: mirror on buf1 (stage t2.Ah0+h1 @P5, t3.Bh0+h1 @P7,
//          t3.Ah0+h1 @P8, vmcnt(8) @P8)
// vmcnt ledger (2 loads/STAGE): steady state enters P1 with 8 in flight
// (t1.B4+t1.A4). @P4: 12 outstanding, vmcnt(4) drains t1 fully before P5
// reads buf1. @P8: 16 outstanding, vmcnt(8) drains t2 fully before next-P1
// reads buf0.

#define BAR()    do { asm volatile("" ::: "memory"); __builtin_amdgcn_s_barrier(); asm volatile("" ::: "memory"); } while (0)
#define WAITV(n) asm volatile("s_waitcnt vmcnt(" #n ")" ::: "memory")

#define STAGE_A(buf, h, kt) do { \
    __builtin_amdgcn_global_load_lds((AS1 const void*)(gA + (size_t)((h) * 128) * KDIM + (kt) * 128), \
        (AS3 void*)(sA + (buf) * 32768 + (h) * 16384 + sdst), 16, 0, 0); \
    __builtin_amdgcn_global_load_lds((AS1 const void*)(gA + (size_t)((h) * 128 + 64) * KDIM + (kt) * 128), \
        (AS3 void*)(sA + (buf) * 32768 + (h) * 16384 + 8192 + sdst), 16, 0, 0); \
} while (0)

#define STAGE_B(buf, h, kt) do { \
    __builtin_amdgcn_global_load_lds((AS1 const void*)(gB + (size_t)((h) * 128) * KDIM + (kt) * 128), \
        (AS3 void*)(sB + (buf) * 32768 + (h) * 16384 + sdst), 16, 0, 0); \
    __builtin_amdgcn_global_load_lds((AS1 const void*)(gB + (size_t)((h) * 128 + 64) * KDIM + (kt) * 128), \
        (AS3 void*)(sB + (buf) * 32768 + (h) * 16384 + 8192 + sdst), 16, 0, 0); \
} while (0)

// A rows wr*128 + mi*16 + lr ; mh0 = mi 0..3 -> aF0, mh1 = mi 4..7 -> aF1
#define READ_A0(buf) do { \
    _Pragma("unroll") for (int mi = 0; mi < 4; ++mi) \
    _Pragma("unroll") for (int ks = 0; ks < 2; ++ks) \
        aF0[mi][ks] = *(const i32x4*)(sA + (buf) * 32768 + rbA + mi * 2048 + co[ks]); \
} while (0)

#define READ_A1(buf) do { \
    _Pragma("unroll") for (int mi = 0; mi < 4; ++mi) \
    _Pragma("unroll") for (int ks = 0; ks < 2; ++ks) \
        aF1[mi][ks] = *(const i32x4*)(sA + (buf) * 32768 + rbA + (4 + mi) * 2048 + co[ks]); \
} while (0)

#define READ_Bb(buf) do { \
    _Pragma("unroll") for (int ni = 0; ni < 4; ++ni) \
    _Pragma("unroll") for (int ks = 0; ks < 2; ++ks) \
        bF[ni][ks] = *(const i32x4*)(sB + (buf) * 32768 + rbB + ni * 2048 + co[ks]); \
} while (0)

// 16 MFMAs per call: 4 mi x 2 nj x 2 ks
#define MMA0(nh) do { \
    __builtin_amdgcn_s_setprio(1); \
    _Pragma("unroll") for (int ks = 0; ks < 2; ++ks) \
    _Pragma("unroll") for (int mi = 0; mi < 4; ++mi) \
    _Pragma("unroll") for (int nj = 0; nj < 2; ++nj) \
        acc[mi][2 * (nh) + nj] = __builtin_amdgcn_mfma_i32_16x16x64_i8( \
            aF0[mi][ks], bF[2 * (nh) + nj][ks], acc[mi][2 * (nh) + nj], 0, 0, 0); \
    __builtin_amdgcn_s_setprio(0); \
} while (0)

#define MMA1(nh) do { \
    __builtin_amdgcn_s_setprio(1); \
    _Pragma("unroll") for (int ks = 0; ks < 2; ++ks) \
    _Pragma("unroll") for (int mi = 0; mi < 4; ++mi) \
    _Pragma("unroll") for (int nj = 0; nj < 2; ++nj) \
        acc[4 + mi][2 * (nh) + nj] = __builtin_amdgcn_mfma_i32_16x16x64_i8( \
            aF1[mi][ks], bF[2 * (nh) + nj][ks], acc[4 + mi][2 * (nh) + nj], 0, 0, 0); \
    __builtin_amdgcn_s_setprio(0); \
} while (0)

__global__ __launch_bounds__(512, 2) void gemm_bt_i8(
        const int8_t* __restrict__ A,    // [M,K] int8
        const int8_t* __restrict__ Bm,   // [N,K] int8
        const float* __restrict__ scales,// [M] = s_m * sw
        const float* __restrict__ bias,  // [N]
        float* __restrict__ C)           // [M,N] fp32
{
    __shared__ __align__(16) int8_t sA[2 * BM * BK];  // 64 KiB
    __shared__ __align__(16) int8_t sB[2 * BN * BK];  // 64 KiB

    const int tid  = threadIdx.x;
    const int wave = tid >> 6;
    const int lane = tid & 63;
    const int wr   = wave >> 2;       // 0..1  (M half)
    const int wc   = wave & 3;        // 0..3  (N quarter)
    const int lr   = lane & 15;       // row within 16-row fragment
    const int lg   = lane >> 4;       // k-group 0..3

    // T1: XCD-aware swizzle over 512 wgs (32 m-tiles x 16 n-tiles); 512%8==0.
    const int orig = blockIdx.y * 16 + blockIdx.x;
    const int nu   = (orig & 7) * 64 + (orig >> 3);
    const int m0   = (nu >> 4) * BM;
    const int n0   = (nu & 15) * BN;

    // ---- staging (linear LDS dest, inverse-swizzled global src) ----
    // dest row = tid>>3 (64 rows per 8 KiB call), phys chunk = tid&7;
    // source logical chunk = phys ^ (((row>>2)&1)<<1), row bit2 = tid bit5.
    const int trow = tid >> 3;
    const int slog = (tid & 7) ^ (((tid >> 5) & 1) << 1);
    const int8_t* gA = A  + (size_t)(m0 + trow) * KDIM + slog * 16;
    const int8_t* gB = Bm + (size_t)(n0 + trow) * KDIM + slog * 16;
    const int sdst = tid * 16;

    // ---- fragment read addresses ----
    const int f = ((lr >> 2) & 1) << 1;           // swizzle term (row bit 2)
    const int rbA = (wr * 128 + lr) * BK;
    const int rbB = (wc * 64  + lr) * BK;
    int co[2];
#pragma unroll
    for (int ks = 0; ks < 2; ++ks) co[ks] = ks * 64 + ((lg ^ f) << 4);

    i32x4 acc[8][4];
#pragma unroll
    for (int mi = 0; mi < 8; ++mi)
#pragma unroll
        for (int ni = 0; ni < 4; ++ni)
#pragma unroll
            for (int r = 0; r < 4; ++r) acc[mi][ni][r] = 0;

    i32x4 aF0[4][2];  // mi 0..3 (live P1-P2)
    i32x4 aF1[4][2];  // mi 4..7 (live P2-P4)
    i32x4 bF[4][2];   // ni 0..3 (live P1-P4)

    // ---- prologue: t0 full + t1 full staged; drain t0, t1 (8 loads) in flight ----
    STAGE_B(0, 0, 0); STAGE_B(0, 1, 0);
    STAGE_A(0, 0, 0); STAGE_A(0, 1, 0);
    STAGE_B(1, 0, 1); STAGE_B(1, 1, 1);
    STAGE_A(1, 0, 1); STAGE_A(1, 1, 1);
    WAITV(8);          // t0 landed; t1 (8 loads) in flight
    BAR();

#pragma unroll 1
    for (int it = 0; it < NKT / 2 - 1; ++it) {     // 15 iterations, tiles 0..29
        const int t2 = 2 * it + 2, t3 = 2 * it + 3;
        // P1: all buf0 reads except A.mh1; counted lgkm lets bF[2..3] flow
        READ_A0(0); READ_Bb(0);                    BAR(); MMA0(0); BAR();
        // P2: A.mh1 reads flow under MMA0(1)
        READ_A1(0);                                BAR(); MMA0(1); BAR();
        // P3: pure MFMA; buf0.B free (all bF reads done by P1-end barrier)
        STAGE_B(0, 0, t2);                         BAR(); MMA1(1); BAR();
        // P4: pure MFMA; drain t1 (staged prev P7/P8, 4-phase distance)
        STAGE_B(0, 1, t2); WAITV(4);               BAR(); MMA1(0); BAR();
        // P5: buf1 reads; buf0.A free (aF1 drained by P3's use + barrier)
        READ_A0(1); READ_Bb(1);
        STAGE_A(0, 0, t2); STAGE_A(0, 1, t2);      BAR(); MMA0(0); BAR();
        // P6
        READ_A1(1);                                BAR(); MMA0(1); BAR();
        // P7: buf1.B free from here
        STAGE_B(1, 0, t3); STAGE_B(1, 1, t3);      BAR(); MMA1(1); BAR();
        // P8: buf1.A free; drain t2 (youngest staged P5, 3 phases)
        STAGE_A(1, 0, t3); STAGE_A(1, 1, t3); WAITV(8); BAR(); MMA1(0); BAR();
    }

    // ---- tail: tiles 30 (buf0) and 31 (buf1); no more staging ----
    // Entering with t31.B + t31.A (8 loads) in flight; WAITV(0) @P4 drains.
    READ_A0(0); READ_Bb(0);                        BAR(); MMA0(0); BAR();
    READ_A1(0);                                    BAR(); MMA0(1); BAR();
                                                   BAR(); MMA1(1); BAR();
    WAITV(0);                                      BAR(); MMA1(0); BAR();
    READ_A0(1); READ_Bb(1);                        BAR(); MMA0(0); BAR();
    READ_A1(1);                                    BAR(); MMA0(1); BAR();
    MMA1(1);
    MMA1(0);

    // ---- epilogue ----
    // C/D 16x16 layout: col = lr, row = lg*4 + r  [m89/m91, dtype-independent]
#pragma unroll
    for (int mi = 0; mi < 8; ++mi) {
        const int row_base = m0 + wr * 128 + mi * 16 + lg * 4;
        float sc[4];
#pragma unroll
        for (int r = 0; r < 4; ++r) sc[r] = scales[row_base + r];
#pragma unroll
        for (int ni = 0; ni < 4; ++ni) {
            const int col = n0 + wc * 64 + ni * 16 + lr;
            const float bc = bias[col];
#pragma unroll
            for (int r = 0; r < 4; ++r)
                C[(size_t)(row_base + r) * NDIM + col] = (float)acc[mi][ni][r] * sc[r] + bc;
        }
    }
}

// ---- correctness fallback if workspace is too small (not expected to run) ----
__global__ void gemm_naive_f32(const float* __restrict__ x, const int* __restrict__ qw,
                               const float* __restrict__ sw, const float* __restrict__ bias,
                               float* __restrict__ out) {
    size_t id = (size_t)blockIdx.x * blockDim.x + threadIdx.x;
    if (id >= (size_t)MDIM * NDIM) return;
    int m = (int)(id / NDIM);
    int n = (int)(id % NDIM);
    const float* xr = x + (size_t)m * KDIM;
    const int*   wr = qw + (size_t)n * KDIM;
    float acc = 0.f;
    for (int k = 0; k < KDIM; k++) acc += xr[k] * (float)wr[k];
    out[id] = acc * (*sw) + bias[n];
}

extern "C" void kernel_launch(void* const* d_in, const int* in_sizes, int n_in,
                              void* d_out, int out_size, void* d_ws, size_t ws_size,
                              hipStream_t stream) {
    const float* x    = (const float*)d_in[0];
    const int*   qw   = (const int*)d_in[1];
    const float* sw   = (const float*)d_in[2];
    const float* bias = (const float*)d_in[3];
    float* out = (float*)d_out;

    const size_t needA = (size_t)MDIM * KDIM;                  // 32 MiB int8
    const size_t needB = (size_t)NDIM * KDIM;                  // 16 MiB int8
    const size_t needS = (size_t)MDIM * sizeof(float);         // 32 KiB scales

    if (ws_size >= needA + needB + needS) {
        int8_t* Aq = (int8_t*)d_ws;
        int8_t* Bq = Aq + needA;
        float*  scales = (float*)(Bq + needB);

        quant_x<<<MDIM, 256, 0, stream>>>(x, sw, Aq, scales);
        const long nw4 = (long)NDIM * KDIM / 4;
        cvt_w<<<(int)(nw4 / 256), 256, 0, stream>>>(qw, Bq);

        dim3 grid(NDIM / BN, MDIM / BM);                       // (16, 32) = 512 blocks
        gemm_bt_i8<<<grid, 512, 0, stream>>>(Aq, Bq, scales, bias, out);
    } else {
        size_t total = (size_t)MDIM * NDIM;
        gemm_naive_f32<<<(total + 255) / 256, 256, 0, stream>>>(x, qw, sw, bias, out);
    }
}

// Round 5
// 402.375 us; speedup vs baseline: 1.0108x; 1.0082x over previous
//
#include <hip/hip_runtime.h>
#include <stdint.h>

// Problem constants (B=4, S=2048, K=4096, N=4096 -> M = B*S = 8192)
#define MDIM 8192
#define NDIM 4096
#define KDIM 4096

// GEMM: 256x256 tile, BK=128, 512 threads = 8 waves (2M x 4N), per-wave
// 128x64 via mfma_i32_16x16x64_i8. Double-buffered LDS (128 KiB).
// R5: SOFTWARE-PIPELINED READS -- every ds_read is issued one phase before
// its consuming MFMA (m201's actual overlap mechanism; R1-R4 consumed reads
// in-phase, serializing LDS port (2800 cyc/tile) against MFMA (2613) ->
// 5812 measured). MMA order rotated (P1:aF0xB01, P2:aF1xB01, P3:aF0xB23,
// P4:aF1xB23) so all operand lifetimes are disjoint -> single-buffered
// registers (24 live i32x4 = 96 VGPR, same as R4; 2 waves/SIMD preserved).
// One barrier/phase; LGKM0 only at the P2 region turnover; vmcnt(2)@P3.
#define BM 256
#define BN 256
#define BK 128
#define NKT (KDIM / BK)   // 32 K-tiles

typedef __attribute__((ext_vector_type(4)))  int i32x4;

#define AS1 __attribute__((address_space(1)))
#define AS3 __attribute__((address_space(3)))

__device__ __forceinline__ int clamp127(int v) {
    return v > 127 ? 127 : (v < -127 ? -127 : v);
}

// ---- x fp32 -> int8, per-row symmetric quant (row = 4096 elems) ----
__global__ __launch_bounds__(256) void quant_x(
        const float* __restrict__ x, const float* __restrict__ sw,
        int8_t* __restrict__ Aq, float* __restrict__ scales) {
    const int row = blockIdx.x;
    const int t   = threadIdx.x;
    const float4* px = (const float4*)(x + (size_t)row * KDIM);

    float4 v[4];
#pragma unroll
    for (int j = 0; j < 4; j++) v[j] = px[t + 256 * j];

    float a = 0.f;
#pragma unroll
    for (int j = 0; j < 4; j++) {
        a = fmaxf(a, fabsf(v[j].x)); a = fmaxf(a, fabsf(v[j].y));
        a = fmaxf(a, fabsf(v[j].z)); a = fmaxf(a, fabsf(v[j].w));
    }
#pragma unroll
    for (int off = 32; off >= 1; off >>= 1)
        a = fmaxf(a, __shfl_xor(a, off));
    __shared__ float red[4];
    if ((t & 63) == 0) red[t >> 6] = a;
    __syncthreads();
    const float amax = fmaxf(fmaxf(red[0], red[1]), fmaxf(red[2], red[3]));
    const float inv  = (amax > 0.f) ? (127.0f / amax) : 0.f;
    if (t == 0) scales[row] = (amax * (1.0f / 127.0f)) * (*sw);

    int* out32 = (int*)(Aq + (size_t)row * KDIM);
#pragma unroll
    for (int j = 0; j < 4; j++) {
        int b0 = clamp127(__float2int_rn(v[j].x * inv));
        int b1 = clamp127(__float2int_rn(v[j].y * inv));
        int b2 = clamp127(__float2int_rn(v[j].z * inv));
        int b3 = clamp127(__float2int_rn(v[j].w * inv));
        out32[t + 256 * j] = (b0 & 255) | ((b1 & 255) << 8) | ((b2 & 255) << 16) | ((b3 & 255) << 24);
    }
}

// ---- qw int32 -> int8 (exact; values already in [-128,127]) ----
__global__ __launch_bounds__(256) void cvt_w(const int* __restrict__ qw, int8_t* __restrict__ Bq) {
    const long i = (long)blockIdx.x * 256 + threadIdx.x;
    int4 a = ((const int4*)qw)[i];
    ((int*)Bq)[i] = (a.x & 255) | ((a.y & 255) << 8) | ((a.z & 255) << 16) | ((a.w & 255) << 24);
}

// ================== 256x256 pipelined-read i8 GEMM (v5) ==================
//
// LDS: [256 rows][128 B]/tile, phys_chunk = chunk ^ (((row>>2)&1)<<1)
// (m201 st_16x32). Linear global_load_lds dest + inverse-swizzled source.
//
// Per-tile phase plan (buf b = t&1; reads ONE PHASE AHEAD of use):
//  P1: rd aF1(t)[b]        | MMA aF0 x bF01 | stage (t+1).Bh0 | BAR
//  P2: rd bF23(t)[b]       | MMA aF1 x bF01 | stage (t+1).Bh1 | LGKM0 BAR
//  P3:                     | MMA aF0 x bF23 | stage (t+2).Ah0 | VMCNT(2) BAR
//  P4: rd aF0,bF01(t+1)[1-b]| MMA aF1 x bF23 | stage (t+2).Ah1 | BAR
// Operand lifetimes (all single-buffered): aF0 rd P4(t-1) used P1,P3;
//  aF1 rd P1 used P2,P4; bF01 rd P4(t-1) used P1,P2; bF23 rd P2 used P3,P4.
// Region ledger: buf(t) reads all drained by P2-end (MMA lgkm + LGKM0) ->
//  stage(t+2).A into buf(t) at P3 is safe. B(t+2) staged next tile's P1/P2.
// vmcnt @P3(t): queue = (t+1).A@P3/P4(t-1)[4] .B@P1/P2(t)[4], (t+2).Ah0@P3[2]
//  -> VMCNT(2) drains all of t+1 before P4 reads it. Prologue: t0 full +
//  t1.A, VMCNT(4). Tail: B31 staged at T30.P1/P2, VMCNT(0) at T30.P3.

#define BAR()    do { asm volatile("" ::: "memory"); __builtin_amdgcn_s_barrier(); asm volatile("" ::: "memory"); } while (0)
#define LGKM0()  asm volatile("s_waitcnt lgkmcnt(0)" ::: "memory")
#define WAITV(n) asm volatile("s_waitcnt vmcnt(" #n ")" ::: "memory")

#define STAGE_A(buf, h, kt) do { \
    __builtin_amdgcn_global_load_lds((AS1 const void*)(gA + (size_t)((h) * 128) * KDIM + (kt) * 128), \
        (AS3 void*)(sA + (buf) * 32768 + (h) * 16384 + sdst), 16, 0, 0); \
    __builtin_amdgcn_global_load_lds((AS1 const void*)(gA + (size_t)((h) * 128 + 64) * KDIM + (kt) * 128), \
        (AS3 void*)(sA + (buf) * 32768 + (h) * 16384 + 8192 + sdst), 16, 0, 0); \
} while (0)

#define STAGE_B(buf, h, kt) do { \
    __builtin_amdgcn_global_load_lds((AS1 const void*)(gB + (size_t)((h) * 128) * KDIM + (kt) * 128), \
        (AS3 void*)(sB + (buf) * 32768 + (h) * 16384 + sdst), 16, 0, 0); \
    __builtin_amdgcn_global_load_lds((AS1 const void*)(gB + (size_t)((h) * 128 + 64) * KDIM + (kt) * 128), \
        (AS3 void*)(sB + (buf) * 32768 + (h) * 16384 + 8192 + sdst), 16, 0, 0); \
} while (0)

// 16x16x64 fragments: lane l -> row l&15, k-chunk l>>4; rows at 128-B stride.
#define READ_A0(buf) do { \
    _Pragma("unroll") for (int mi = 0; mi < 4; ++mi) \
    _Pragma("unroll") for (int ks = 0; ks < 2; ++ks) \
        aF0[mi][ks] = *(const i32x4*)(sA + (buf) * 32768 + rbA + mi * 2048 + co[ks]); \
} while (0)

#define READ_A1(buf) do { \
    _Pragma("unroll") for (int mi = 0; mi < 4; ++mi) \
    _Pragma("unroll") for (int ks = 0; ks < 2; ++ks) \
        aF1[mi][ks] = *(const i32x4*)(sA + (buf) * 32768 + rbA + (4 + mi) * 2048 + co[ks]); \
} while (0)

#define READ_B01(buf) do { \
    _Pragma("unroll") for (int ni = 0; ni < 2; ++ni) \
    _Pragma("unroll") for (int ks = 0; ks < 2; ++ks) \
        bF01[ni][ks] = *(const i32x4*)(sB + (buf) * 32768 + rbB + ni * 2048 + co[ks]); \
} while (0)

#define READ_B23(buf) do { \
    _Pragma("unroll") for (int ni = 0; ni < 2; ++ni) \
    _Pragma("unroll") for (int ks = 0; ks < 2; ++ks) \
        bF23[ni][ks] = *(const i32x4*)(sB + (buf) * 32768 + rbB + (2 + ni) * 2048 + co[ks]); \
} while (0)

// 16 MFMAs per call: 4 mi x 2 nj x 2 ks.  nh selects bF01 (0) or bF23 (1).
#define MMA_(AF, accbase, BF, nhofs) do { \
    __builtin_amdgcn_s_setprio(1); \
    _Pragma("unroll") for (int ks = 0; ks < 2; ++ks) \
    _Pragma("unroll") for (int mi = 0; mi < 4; ++mi) \
    _Pragma("unroll") for (int nj = 0; nj < 2; ++nj) \
        acc[(accbase) + mi][(nhofs) + nj] = __builtin_amdgcn_mfma_i32_16x16x64_i8( \
            AF[mi][ks], BF[nj][ks], acc[(accbase) + mi][(nhofs) + nj], 0, 0, 0); \
    __builtin_amdgcn_s_setprio(0); \
} while (0)

__global__ __launch_bounds__(512, 2) void gemm_bt_i8(
        const int8_t* __restrict__ A,    // [M,K] int8
        const int8_t* __restrict__ Bm,   // [N,K] int8
        const float* __restrict__ scales,// [M] = s_m * sw
        const float* __restrict__ bias,  // [N]
        float* __restrict__ C)           // [M,N] fp32
{
    __shared__ __align__(16) int8_t sA[2 * BM * BK];  // 64 KiB
    __shared__ __align__(16) int8_t sB[2 * BN * BK];  // 64 KiB

    const int tid  = threadIdx.x;
    const int wave = tid >> 6;
    const int lane = tid & 63;
    const int wr   = wave >> 2;       // 0..1  (M half)
    const int wc   = wave & 3;        // 0..3  (N quarter)
    const int lr   = lane & 15;       // row within 16-row fragment
    const int lg   = lane >> 4;       // k-group 0..3

    // T1: XCD-aware swizzle over 512 wgs (32 m-tiles x 16 n-tiles); 512%8==0.
    const int orig = blockIdx.y * 16 + blockIdx.x;
    const int nu   = (orig & 7) * 64 + (orig >> 3);
    const int m0   = (nu >> 4) * BM;
    const int n0   = (nu & 15) * BN;

    // ---- staging (linear LDS dest, inverse-swizzled global src) ----
    const int trow = tid >> 3;
    const int slog = (tid & 7) ^ (((tid >> 5) & 1) << 1);
    const int8_t* gA = A  + (size_t)(m0 + trow) * KDIM + slog * 16;
    const int8_t* gB = Bm + (size_t)(n0 + trow) * KDIM + slog * 16;
    const int sdst = tid * 16;

    // ---- fragment read addresses ----
    const int f = ((lr >> 2) & 1) << 1;           // swizzle term (row bit 2)
    const int rbA = (wr * 128 + lr) * BK;
    const int rbB = (wc * 64  + lr) * BK;
    int co[2];
#pragma unroll
    for (int ks = 0; ks < 2; ++ks) co[ks] = ks * 64 + ((lg ^ f) << 4);

    i32x4 acc[8][4];
#pragma unroll
    for (int mi = 0; mi < 8; ++mi)
#pragma unroll
        for (int ni = 0; ni < 4; ++ni)
#pragma unroll
            for (int r = 0; r < 4; ++r) acc[mi][ni][r] = 0;

    i32x4 aF0[4][2];   // rd P4(t-1), used P1,P3(t)
    i32x4 aF1[4][2];   // rd P1(t),   used P2,P4(t)
    i32x4 bF01[2][2];  // rd P4(t-1), used P1,P2(t)
    i32x4 bF23[2][2];  // rd P2(t),   used P3,P4(t)

    // ---- prologue: t0 full + t1.A staged; drain t0; pre-read P1(0) operands ----
    STAGE_A(0, 0, 0); STAGE_A(0, 1, 0);
    STAGE_B(0, 0, 0); STAGE_B(0, 1, 0);
    STAGE_A(1, 0, 1); STAGE_A(1, 1, 1);
    WAITV(4);          // t0 (8 loads) landed; t1.A (4) in flight
    BAR();
    READ_A0(0); READ_B01(0);   // operands for P1(0), consumed via counted lgkm

#pragma unroll 1
    for (int it = 0; it < NKT / 2 - 1; ++it) {     // 15 iters, tiles e=2it, o=e+1 (0..29)
        const int e = 2 * it;
        // ---- tile e (buf0) ----
        READ_A1(0);                 MMA_(aF0, 0, bF01, 0); STAGE_B(1, 0, e + 1); BAR();
        READ_B23(0);                MMA_(aF1, 4, bF01, 0); STAGE_B(1, 1, e + 1); LGKM0(); BAR();
                                    MMA_(aF0, 0, bF23, 2); STAGE_A(0, 0, e + 2); WAITV(2); BAR();
        READ_A0(1); READ_B01(1);    MMA_(aF1, 4, bF23, 2); STAGE_A(0, 1, e + 2); BAR();
        // ---- tile o (buf1) ----
        READ_A1(1);                 MMA_(aF0, 0, bF01, 0); STAGE_B(0, 0, e + 2); BAR();
        READ_B23(1);                MMA_(aF1, 4, bF01, 0); STAGE_B(0, 1, e + 2); LGKM0(); BAR();
                                    MMA_(aF0, 0, bF23, 2); STAGE_A(1, 0, e + 3); WAITV(2); BAR();
        READ_A0(0); READ_B01(0);    MMA_(aF1, 4, bF23, 2); STAGE_A(1, 1, e + 3); BAR();
    }

    // ---- tail: tile 30 (buf0; stage B31, then full drain) + tile 31 (buf1) ----
    READ_A1(0);                 MMA_(aF0, 0, bF01, 0); STAGE_B(1, 0, 31); BAR();
    READ_B23(0);                MMA_(aF1, 4, bF01, 0); STAGE_B(1, 1, 31); LGKM0(); BAR();
                                MMA_(aF0, 0, bF23, 2); WAITV(0); BAR();
    READ_A0(1); READ_B01(1);    MMA_(aF1, 4, bF23, 2); BAR();
    READ_A1(1);                 MMA_(aF0, 0, bF01, 0); BAR();
    READ_B23(1);                MMA_(aF1, 4, bF01, 0); BAR();
                                MMA_(aF0, 0, bF23, 2);
                                MMA_(aF1, 4, bF23, 2);

    // ---- epilogue ----
    // C/D 16x16 layout: col = lr, row = lg*4 + r  [m89/m91, dtype-independent]
#pragma unroll
    for (int mi = 0; mi < 8; ++mi) {
        const int row_base = m0 + wr * 128 + mi * 16 + lg * 4;
        float sc[4];
#pragma unroll
        for (int r = 0; r < 4; ++r) sc[r] = scales[row_base + r];
#pragma unroll
        for (int ni = 0; ni < 4; ++ni) {
            const int col = n0 + wc * 64 + ni * 16 + lr;
            const float bc = bias[col];
#pragma unroll
            for (int r = 0; r < 4; ++r)
                C[(size_t)(row_base + r) * NDIM + col] = (float)acc[mi][ni][r] * sc[r] + bc;
        }
    }
}

// ---- correctness fallback if workspace is too small (not expected to run) ----
__global__ void gemm_naive_f32(const float* __restrict__ x, const int* __restrict__ qw,
                               const float* __restrict__ sw, const float* __restrict__ bias,
                               float* __restrict__ out) {
    size_t id = (size_t)blockIdx.x * blockDim.x + threadIdx.x;
    if (id >= (size_t)MDIM * NDIM) return;
    int m = (int)(id / NDIM);
    int n = (int)(id % NDIM);
    const float* xr = x + (size_t)m * KDIM;
    const int*   wr = qw + (size_t)n * KDIM;
    float acc = 0.f;
    for (int k = 0; k < KDIM; k++) acc += xr[k] * (float)wr[k];
    out[id] = acc * (*sw) + bias[n];
}

extern "C" void kernel_launch(void* const* d_in, const int* in_sizes, int n_in,
                              void* d_out, int out_size, void* d_ws, size_t ws_size,
                              hipStream_t stream) {
    const float* x    = (const float*)d_in[0];
    const int*   qw   = (const int*)d_in[1];
    const float* sw   = (const float*)d_in[2];
    const float* bias = (const float*)d_in[3];
    float* out = (float*)d_out;

    const size_t needA = (size_t)MDIM * KDIM;                  // 32 MiB int8
    const size_t needB = (size_t)NDIM * KDIM;                  // 16 MiB int8
    const size_t needS = (size_t)MDIM * sizeof(float);         // 32 KiB scales

    if (ws_size >= needA + needB + needS) {
        int8_t* Aq = (int8_t*)d_ws;
        int8_t* Bq = Aq + needA;
        float*  scales = (float*)(Bq + needB);

        quant_x<<<MDIM, 256, 0, stream>>>(x, sw, Aq, scales);
        const long nw4 = (long)NDIM * KDIM / 4;
        cvt_w<<<(int)(nw4 / 256), 256, 0, stream>>>(qw, Bq);

        dim3 grid(NDIM / BN, MDIM / BM);                       // (16, 32) = 512 blocks
        gemm_bt_i8<<<grid, 512, 0, stream>>>(Aq, Bq, scales, bias, out);
    } else {
        size_t total = (size_t)MDIM * NDIM;
        gemm_naive_f32<<<(total + 255) / 256, 256, 0, stream>>>(x, qw, sw, bias, out);
    }
}

// Round 6
// 399.658 us; speedup vs baseline: 1.0177x; 1.0068x over previous
//
#include <hip/hip_runtime.h>
#include <stdint.h>

// Problem constants (B=4, S=2048, K=4096, N=4096 -> M = B*S = 8192)
#define MDIM 8192
#define NDIM 4096
#define KDIM 4096

// GEMM: 256x256 tile, BK=128, 512 threads = 8 waves (2M x 4N), per-wave
// 128x64 via mfma_i32_16x16x64_i8. Double-buffered LDS (128 KiB).
// R5: software-pipelined reads (each ds_read one phase before its MFMA).
// R6: FULL 3-bit LDS XOR swizzle, phys_chunk = logical_chunk ^ (row&7).
//   R5's 1-bit st_16x32 left each 16-lane read group on 2 of 8 chunk
//   positions -> 8-way bank conflict, measured 4.0 extra cyc per
//   ds_read_b128 (1.258e7 total; m201-equivalent bf16 logs 0.085/read).
//   With the 16x16 fragment (rows 0..15 per group), row&7 spreads the 16
//   lanes over all 8 chunks exactly twice -> 2-way = free (m136).
//   Both-sides rule: staging source chunk = (tid&7)^((tid>>3)&7).
#define BM 256
#define BN 256
#define BK 128
#define NKT (KDIM / BK)   // 32 K-tiles

typedef __attribute__((ext_vector_type(4)))  int i32x4;

#define AS1 __attribute__((address_space(1)))
#define AS3 __attribute__((address_space(3)))

__device__ __forceinline__ int clamp127(int v) {
    return v > 127 ? 127 : (v < -127 ? -127 : v);
}

// ---- x fp32 -> int8, per-row symmetric quant (row = 4096 elems) ----
__global__ __launch_bounds__(256) void quant_x(
        const float* __restrict__ x, const float* __restrict__ sw,
        int8_t* __restrict__ Aq, float* __restrict__ scales) {
    const int row = blockIdx.x;
    const int t   = threadIdx.x;
    const float4* px = (const float4*)(x + (size_t)row * KDIM);

    float4 v[4];
#pragma unroll
    for (int j = 0; j < 4; j++) v[j] = px[t + 256 * j];

    float a = 0.f;
#pragma unroll
    for (int j = 0; j < 4; j++) {
        a = fmaxf(a, fabsf(v[j].x)); a = fmaxf(a, fabsf(v[j].y));
        a = fmaxf(a, fabsf(v[j].z)); a = fmaxf(a, fabsf(v[j].w));
    }
#pragma unroll
    for (int off = 32; off >= 1; off >>= 1)
        a = fmaxf(a, __shfl_xor(a, off));
    __shared__ float red[4];
    if ((t & 63) == 0) red[t >> 6] = a;
    __syncthreads();
    const float amax = fmaxf(fmaxf(red[0], red[1]), fmaxf(red[2], red[3]));
    const float inv  = (amax > 0.f) ? (127.0f / amax) : 0.f;
    if (t == 0) scales[row] = (amax * (1.0f / 127.0f)) * (*sw);

    int* out32 = (int*)(Aq + (size_t)row * KDIM);
#pragma unroll
    for (int j = 0; j < 4; j++) {
        int b0 = clamp127(__float2int_rn(v[j].x * inv));
        int b1 = clamp127(__float2int_rn(v[j].y * inv));
        int b2 = clamp127(__float2int_rn(v[j].z * inv));
        int b3 = clamp127(__float2int_rn(v[j].w * inv));
        out32[t + 256 * j] = (b0 & 255) | ((b1 & 255) << 8) | ((b2 & 255) << 16) | ((b3 & 255) << 24);
    }
}

// ---- qw int32 -> int8 (exact; values already in [-128,127]) ----
__global__ __launch_bounds__(256) void cvt_w(const int* __restrict__ qw, int8_t* __restrict__ Bq) {
    const long i = (long)blockIdx.x * 256 + threadIdx.x;
    int4 a = ((const int4*)qw)[i];
    ((int*)Bq)[i] = (a.x & 255) | ((a.y & 255) << 8) | ((a.z & 255) << 16) | ((a.w & 255) << 24);
}

// ================== 256x256 pipelined-read i8 GEMM (v6) ==================
//
// LDS: [256 rows][128 B]/tile, phys_chunk = logical_chunk ^ (row & 7)
// (full 3-bit XOR; G4 recipe for 128-B rows). Linear global_load_lds dest +
// inverse-swizzled global source (rule #21; XOR is an involution).
//
// Per-tile phase plan (buf b = t&1; reads ONE PHASE AHEAD of use):
//  P1: rd aF1(t)[b]        | MMA aF0 x bF01 | stage (t+1).Bh0 | BAR
//  P2: rd bF23(t)[b]       | MMA aF1 x bF01 | stage (t+1).Bh1 | LGKM0 BAR
//  P3:                     | MMA aF0 x bF23 | stage (t+2).Ah0 | VMCNT(2) BAR
//  P4: rd aF0,bF01(t+1)[1-b]| MMA aF1 x bF23 | stage (t+2).Ah1 | BAR
// Operand lifetimes all disjoint (single-buffered registers).
// Region ledger: buf(t) reads drained by P2-end -> stage(t+2).A @P3 safe;
// B(t+2) staged next tile's P1/P2. vmcnt@P3(t): queue = (t+1).A[4],
// (t+1).B[4], (t+2).Ah0[2] -> VMCNT(2) drains tile t+1 before P4 reads it.
// Prologue: t0 full + t1.A, VMCNT(4). Tail: B31 @T30.P1/P2, VMCNT(0) @T30.P3.

#define BAR()    do { asm volatile("" ::: "memory"); __builtin_amdgcn_s_barrier(); asm volatile("" ::: "memory"); } while (0)
#define LGKM0()  asm volatile("s_waitcnt lgkmcnt(0)" ::: "memory")
#define WAITV(n) asm volatile("s_waitcnt vmcnt(" #n ")" ::: "memory")

#define STAGE_A(buf, h, kt) do { \
    __builtin_amdgcn_global_load_lds((AS1 const void*)(gA + (size_t)((h) * 128) * KDIM + (kt) * 128), \
        (AS3 void*)(sA + (buf) * 32768 + (h) * 16384 + sdst), 16, 0, 0); \
    __builtin_amdgcn_global_load_lds((AS1 const void*)(gA + (size_t)((h) * 128 + 64) * KDIM + (kt) * 128), \
        (AS3 void*)(sA + (buf) * 32768 + (h) * 16384 + 8192 + sdst), 16, 0, 0); \
} while (0)

#define STAGE_B(buf, h, kt) do { \
    __builtin_amdgcn_global_load_lds((AS1 const void*)(gB + (size_t)((h) * 128) * KDIM + (kt) * 128), \
        (AS3 void*)(sB + (buf) * 32768 + (h) * 16384 + sdst), 16, 0, 0); \
    __builtin_amdgcn_global_load_lds((AS1 const void*)(gB + (size_t)((h) * 128 + 64) * KDIM + (kt) * 128), \
        (AS3 void*)(sB + (buf) * 32768 + (h) * 16384 + 8192 + sdst), 16, 0, 0); \
} while (0)

// 16x16x64 fragments: lane l -> row l&15, k-chunk l>>4; rows at 128-B stride.
#define READ_A0(buf) do { \
    _Pragma("unroll") for (int mi = 0; mi < 4; ++mi) \
    _Pragma("unroll") for (int ks = 0; ks < 2; ++ks) \
        aF0[mi][ks] = *(const i32x4*)(sA + (buf) * 32768 + rbA + mi * 2048 + co[ks]); \
} while (0)

#define READ_A1(buf) do { \
    _Pragma("unroll") for (int mi = 0; mi < 4; ++mi) \
    _Pragma("unroll") for (int ks = 0; ks < 2; ++ks) \
        aF1[mi][ks] = *(const i32x4*)(sA + (buf) * 32768 + rbA + (4 + mi) * 2048 + co[ks]); \
} while (0)

#define READ_B01(buf) do { \
    _Pragma("unroll") for (int ni = 0; ni < 2; ++ni) \
    _Pragma("unroll") for (int ks = 0; ks < 2; ++ks) \
        bF01[ni][ks] = *(const i32x4*)(sB + (buf) * 32768 + rbB + ni * 2048 + co[ks]); \
} while (0)

#define READ_B23(buf) do { \
    _Pragma("unroll") for (int ni = 0; ni < 2; ++ni) \
    _Pragma("unroll") for (int ks = 0; ks < 2; ++ks) \
        bF23[ni][ks] = *(const i32x4*)(sB + (buf) * 32768 + rbB + (2 + ni) * 2048 + co[ks]); \
} while (0)

// 16 MFMAs per call: 4 mi x 2 nj x 2 ks.  nhofs selects bF01 (0) or bF23 (2).
#define MMA_(AF, accbase, BF, nhofs) do { \
    __builtin_amdgcn_s_setprio(1); \
    _Pragma("unroll") for (int ks = 0; ks < 2; ++ks) \
    _Pragma("unroll") for (int mi = 0; mi < 4; ++mi) \
    _Pragma("unroll") for (int nj = 0; nj < 2; ++nj) \
        acc[(accbase) + mi][(nhofs) + nj] = __builtin_amdgcn_mfma_i32_16x16x64_i8( \
            AF[mi][ks], BF[nj][ks], acc[(accbase) + mi][(nhofs) + nj], 0, 0, 0); \
    __builtin_amdgcn_s_setprio(0); \
} while (0)

__global__ __launch_bounds__(512, 2) void gemm_bt_i8(
        const int8_t* __restrict__ A,    // [M,K] int8
        const int8_t* __restrict__ Bm,   // [N,K] int8
        const float* __restrict__ scales,// [M] = s_m * sw
        const float* __restrict__ bias,  // [N]
        float* __restrict__ C)           // [M,N] fp32
{
    __shared__ __align__(16) int8_t sA[2 * BM * BK];  // 64 KiB
    __shared__ __align__(16) int8_t sB[2 * BN * BK];  // 64 KiB

    const int tid  = threadIdx.x;
    const int wave = tid >> 6;
    const int lane = tid & 63;
    const int wr   = wave >> 2;       // 0..1  (M half)
    const int wc   = wave & 3;        // 0..3  (N quarter)
    const int lr   = lane & 15;       // row within 16-row fragment
    const int lg   = lane >> 4;       // k-group 0..3

    // T1: XCD-aware swizzle over 512 wgs (32 m-tiles x 16 n-tiles); 512%8==0.
    const int orig = blockIdx.y * 16 + blockIdx.x;
    const int nu   = (orig & 7) * 64 + (orig >> 3);
    const int m0   = (nu >> 4) * BM;
    const int n0   = (nu & 15) * BN;

    // ---- staging (linear LDS dest, inverse-swizzled global src) ----
    // dest row = tid>>3, dest phys chunk = tid&7; data for phys chunk p of
    // row r is logical chunk p ^ (r&7) -> source chunk = (tid&7)^((tid>>3)&7).
    const int trow = tid >> 3;
    const int slog = (tid & 7) ^ ((tid >> 3) & 7);
    const int8_t* gA = A  + (size_t)(m0 + trow) * KDIM + slog * 16;
    const int8_t* gB = Bm + (size_t)(n0 + trow) * KDIM + slog * 16;
    const int sdst = tid * 16;

    // ---- fragment read addresses ----
    // row = base(≡0 mod 16) + lr  ->  row&7 = lr&7 for both A and B.
    // logical chunk = ks*4 + lg  ->  phys = (ks*4+lg) ^ (lr&7).
    // Per 16-lane group (fixed lg,ks): rows 0..15 -> chunks hit exactly 2x
    // each -> 2 words/bank = 2-way = free (m136).
    const int f3 = lr & 7;
    const int rbA = (wr * 128 + lr) * BK;
    const int rbB = (wc * 64  + lr) * BK;
    int co[2];
#pragma unroll
    for (int ks = 0; ks < 2; ++ks) co[ks] = (((ks << 2) | lg) ^ f3) << 4;

    i32x4 acc[8][4];
#pragma unroll
    for (int mi = 0; mi < 8; ++mi)
#pragma unroll
        for (int ni = 0; ni < 4; ++ni)
#pragma unroll
            for (int r = 0; r < 4; ++r) acc[mi][ni][r] = 0;

    i32x4 aF0[4][2];   // rd P4(t-1), used P1,P3(t)
    i32x4 aF1[4][2];   // rd P1(t),   used P2,P4(t)
    i32x4 bF01[2][2];  // rd P4(t-1), used P1,P2(t)
    i32x4 bF23[2][2];  // rd P2(t),   used P3,P4(t)

    // ---- prologue: t0 full + t1.A staged; drain t0; pre-read P1(0) operands ----
    STAGE_A(0, 0, 0); STAGE_A(0, 1, 0);
    STAGE_B(0, 0, 0); STAGE_B(0, 1, 0);
    STAGE_A(1, 0, 1); STAGE_A(1, 1, 1);
    WAITV(4);          // t0 (8 loads) landed; t1.A (4) in flight
    BAR();
    READ_A0(0); READ_B01(0);   // operands for P1(0), consumed via counted lgkm

#pragma unroll 1
    for (int it = 0; it < NKT / 2 - 1; ++it) {     // 15 iters, tiles e=2it, o=e+1 (0..29)
        const int e = 2 * it;
        // ---- tile e (buf0) ----
        READ_A1(0);                 MMA_(aF0, 0, bF01, 0); STAGE_B(1, 0, e + 1); BAR();
        READ_B23(0);                MMA_(aF1, 4, bF01, 0); STAGE_B(1, 1, e + 1); LGKM0(); BAR();
                                    MMA_(aF0, 0, bF23, 2); STAGE_A(0, 0, e + 2); WAITV(2); BAR();
        READ_A0(1); READ_B01(1);    MMA_(aF1, 4, bF23, 2); STAGE_A(0, 1, e + 2); BAR();
        // ---- tile o (buf1) ----
        READ_A1(1);                 MMA_(aF0, 0, bF01, 0); STAGE_B(0, 0, e + 2); BAR();
        READ_B23(1);                MMA_(aF1, 4, bF01, 0); STAGE_B(0, 1, e + 2); LGKM0(); BAR();
                                    MMA_(aF0, 0, bF23, 2); STAGE_A(1, 0, e + 3); WAITV(2); BAR();
        READ_A0(0); READ_B01(0);    MMA_(aF1, 4, bF23, 2); STAGE_A(1, 1, e + 3); BAR();
    }

    // ---- tail: tile 30 (buf0; stage B31, then full drain) + tile 31 (buf1) ----
    READ_A1(0);                 MMA_(aF0, 0, bF01, 0); STAGE_B(1, 0, 31); BAR();
    READ_B23(0);                MMA_(aF1, 4, bF01, 0); STAGE_B(1, 1, 31); LGKM0(); BAR();
                                MMA_(aF0, 0, bF23, 2); WAITV(0); BAR();
    READ_A0(1); READ_B01(1);    MMA_(aF1, 4, bF23, 2); BAR();
    READ_A1(1);                 MMA_(aF0, 0, bF01, 0); BAR();
    READ_B23(1);                MMA_(aF1, 4, bF01, 0); BAR();
                                MMA_(aF0, 0, bF23, 2);
                                MMA_(aF1, 4, bF23, 2);

    // ---- epilogue ----
    // C/D 16x16 layout: col = lr, row = lg*4 + r  [m89/m91, dtype-independent]
#pragma unroll
    for (int mi = 0; mi < 8; ++mi) {
        const int row_base = m0 + wr * 128 + mi * 16 + lg * 4;
        float sc[4];
#pragma unroll
        for (int r = 0; r < 4; ++r) sc[r] = scales[row_base + r];
#pragma unroll
        for (int ni = 0; ni < 4; ++ni) {
            const int col = n0 + wc * 64 + ni * 16 + lr;
            const float bc = bias[col];
#pragma unroll
            for (int r = 0; r < 4; ++r)
                C[(size_t)(row_base + r) * NDIM + col] = (float)acc[mi][ni][r] * sc[r] + bc;
        }
    }
}

// ---- correctness fallback if workspace is too small (not expected to run) ----
__global__ void gemm_naive_f32(const float* __restrict__ x, const int* __restrict__ qw,
                               const float* __restrict__ sw, const float* __restrict__ bias,
                               float* __restrict__ out) {
    size_t id = (size_t)blockIdx.x * blockDim.x + threadIdx.x;
    if (id >= (size_t)MDIM * NDIM) return;
    int m = (int)(id / NDIM);
    int n = (int)(id % NDIM);
    const float* xr = x + (size_t)m * KDIM;
    const int*   wr = qw + (size_t)n * KDIM;
    float acc = 0.f;
    for (int k = 0; k < KDIM; k++) acc += xr[k] * (float)wr[k];
    out[id] = acc * (*sw) + bias[n];
}

extern "C" void kernel_launch(void* const* d_in, const int* in_sizes, int n_in,
                              void* d_out, int out_size, void* d_ws, size_t ws_size,
                              hipStream_t stream) {
    const float* x    = (const float*)d_in[0];
    const int*   qw   = (const int*)d_in[1];
    const float* sw   = (const float*)d_in[2];
    const float* bias = (const float*)d_in[3];
    float* out = (float*)d_out;

    const size_t needA = (size_t)MDIM * KDIM;                  // 32 MiB int8
    const size_t needB = (size_t)NDIM * KDIM;                  // 16 MiB int8
    const size_t needS = (size_t)MDIM * sizeof(float);         // 32 KiB scales

    if (ws_size >= needA + needB + needS) {
        int8_t* Aq = (int8_t*)d_ws;
        int8_t* Bq = Aq + needA;
        float*  scales = (float*)(Bq + needB);

        quant_x<<<MDIM, 256, 0, stream>>>(x, sw, Aq, scales);
        const long nw4 = (long)NDIM * KDIM / 4;
        cvt_w<<<(int)(nw4 / 256), 256, 0, stream>>>(qw, Bq);

        dim3 grid(NDIM / BN, MDIM / BM);                       // (16, 32) = 512 blocks
        gemm_bt_i8<<<grid, 512, 0, stream>>>(Aq, Bq, scales, bias, out);
    } else {
        size_t total = (size_t)MDIM * NDIM;
        gemm_naive_f32<<<(total + 255) / 256, 256, 0, stream>>>(x, qw, sw, bias, out);
    }
}

// Round 7
// 391.431 us; speedup vs baseline: 1.0391x; 1.0210x over previous
//
#include <hip/hip_runtime.h>
#include <stdint.h>

// Problem constants (B=4, S=2048, K=4096, N=4096 -> M = B*S = 8192)
#define MDIM 8192
#define NDIM 4096
#define KDIM 4096

// GEMM: 256x256 tile, BK=128, 512 threads = 8 waves (2M x 4N), per-wave
// 128x64 via mfma_i32_16x16x64_i8. Double-buffered LDS (128 KiB).
// R5: pipelined reads (>=1 phase ahead). R6: 3-bit XOR swizzle -> bank
// conflicts measured 0. R7: BALANCED read schedule {8,4,8,4}/wave/phase
// (was {8,4,0,12}: the 12-read next-buf cluster at P4 = 768 port-cyc > 653
// MFMA-cyc overflowed its phase and stalled P1's first MFMA ~700 cyc).
// Enabled by splitting the vmcnt drain: A(t+1) certified @P2-end (WAITV 4,
// 2.3-phase distance), B(t+1) @P3-end (WAITV 2) -> aF0' reads at P3,
// bF01' at P4. MMA re-paired so each operand is read a full phase early.
#define BM 256
#define BN 256
#define BK 128
#define NKT (KDIM / BK)   // 32 K-tiles

typedef __attribute__((ext_vector_type(4)))  int i32x4;

#define AS1 __attribute__((address_space(1)))
#define AS3 __attribute__((address_space(3)))

__device__ __forceinline__ int clamp127(int v) {
    return v > 127 ? 127 : (v < -127 ? -127 : v);
}

// ---- x fp32 -> int8, per-row symmetric quant (row = 4096 elems) ----
__global__ __launch_bounds__(256) void quant_x(
        const float* __restrict__ x, const float* __restrict__ sw,
        int8_t* __restrict__ Aq, float* __restrict__ scales) {
    const int row = blockIdx.x;
    const int t   = threadIdx.x;
    const float4* px = (const float4*)(x + (size_t)row * KDIM);

    float4 v[4];
#pragma unroll
    for (int j = 0; j < 4; j++) v[j] = px[t + 256 * j];

    float a = 0.f;
#pragma unroll
    for (int j = 0; j < 4; j++) {
        a = fmaxf(a, fabsf(v[j].x)); a = fmaxf(a, fabsf(v[j].y));
        a = fmaxf(a, fabsf(v[j].z)); a = fmaxf(a, fabsf(v[j].w));
    }
#pragma unroll
    for (int off = 32; off >= 1; off >>= 1)
        a = fmaxf(a, __shfl_xor(a, off));
    __shared__ float red[4];
    if ((t & 63) == 0) red[t >> 6] = a;
    __syncthreads();
    const float amax = fmaxf(fmaxf(red[0], red[1]), fmaxf(red[2], red[3]));
    const float inv  = (amax > 0.f) ? (127.0f / amax) : 0.f;
    if (t == 0) scales[row] = (amax * (1.0f / 127.0f)) * (*sw);

    int* out32 = (int*)(Aq + (size_t)row * KDIM);
#pragma unroll
    for (int j = 0; j < 4; j++) {
        int b0 = clamp127(__float2int_rn(v[j].x * inv));
        int b1 = clamp127(__float2int_rn(v[j].y * inv));
        int b2 = clamp127(__float2int_rn(v[j].z * inv));
        int b3 = clamp127(__float2int_rn(v[j].w * inv));
        out32[t + 256 * j] = (b0 & 255) | ((b1 & 255) << 8) | ((b2 & 255) << 16) | ((b3 & 255) << 24);
    }
}

// ---- qw int32 -> int8 (exact; values already in [-128,127]) ----
__global__ __launch_bounds__(256) void cvt_w(const int* __restrict__ qw, int8_t* __restrict__ Bq) {
    const long i = (long)blockIdx.x * 256 + threadIdx.x;
    int4 a = ((const int4*)qw)[i];
    ((int*)Bq)[i] = (a.x & 255) | ((a.y & 255) << 8) | ((a.z & 255) << 16) | ((a.w & 255) << 24);
}

// ================== 256x256 balanced-phase i8 GEMM (v7) ==================
//
// LDS: [256 rows][128 B]/tile, phys_chunk = logical_chunk ^ (row & 7).
// Linear global_load_lds dest + inverse-swizzled global source (rule #21).
//
// Steady-state per tile t (buf b = t&1; 4 phases, one barrier each):
//  P1: rd bF23(t)[4]+aF1a(t)[4] | MMA aF0xbF01 | stage B(t+1)h0 | BAR
//  P2: rd aF1b(t)[4]            | MMA aF0xbF23 | stage B(t+1)h1 | LGKM0 WAITV(4) BAR
//  P3: rd aF0(t+1)[8]           | MMA aF1xbF01 | stage A(t+2)h0 | WAITV(2) BAR
//  P4: rd bF01(t+1)[4]          | MMA aF1xbF23 | stage A(t+2)h1 | BAR
// Port load per phase (8 waves): P1 576, P2 320, P3 576, P4 320 cyc -- all
// under the 653-cyc MFMA phase; every operand is read >=1 phase before use.
// Reg lifetimes (disjoint, single-buffered): aF0 rd P3(t-1) use P1,P2;
//  aF1 rd P1,P2 use P3,P4; bF01 rd P4(t-1) use P1,P3; bF23 rd P1 use P2,P4.
// vmcnt ledger (2 loads/STAGE, oldest-first):
//  @P2(t)-end: [A(t+1)h0@P3(t-1), A(t+1)h1@P4(t-1), B(t+1)h0@P1(t),
//   B(t+1)h1@P2(t)] = 8 -> WAITV(4) drains A(t+1) for P3's aF0' reads.
//  @P3(t)-end: [B(t+1)h0, B(t+1)h1, A(t+2)h0@P3(t)] = 6 -> WAITV(2)
//   drains B(t+1) for P4's bF01' reads.
// Region ledger: LGKM0@P2(t)-end certifies all buf reads through P2 are
//  complete across waves -> stage A(t+2) into buf(t).A @P3/P4 safe (last
//  buf(t).A read = aF1b@P2); stage B(t+1) into buf(t+1).B @P1/P2 safe
//  (last read bF23(t-1)@P1(t-1), certified by LGKM0@P2(t-1)).
// Prologue: t0 full + A(t1); WAITV(4). Tail: B31 @T30 P1/P2, WAITV(0)@T30 P3.

#define BAR()    do { asm volatile("" ::: "memory"); __builtin_amdgcn_s_barrier(); asm volatile("" ::: "memory"); } while (0)
#define LGKM0()  asm volatile("s_waitcnt lgkmcnt(0)" ::: "memory")
#define WAITV(n) asm volatile("s_waitcnt vmcnt(" #n ")" ::: "memory")

#define STAGE_A(buf, h, kt) do { \
    __builtin_amdgcn_global_load_lds((AS1 const void*)(gA + (size_t)((h) * 128) * KDIM + (kt) * 128), \
        (AS3 void*)(sA + (buf) * 32768 + (h) * 16384 + sdst), 16, 0, 0); \
    __builtin_amdgcn_global_load_lds((AS1 const void*)(gA + (size_t)((h) * 128 + 64) * KDIM + (kt) * 128), \
        (AS3 void*)(sA + (buf) * 32768 + (h) * 16384 + 8192 + sdst), 16, 0, 0); \
} while (0)

#define STAGE_B(buf, h, kt) do { \
    __builtin_amdgcn_global_load_lds((AS1 const void*)(gB + (size_t)((h) * 128) * KDIM + (kt) * 128), \
        (AS3 void*)(sB + (buf) * 32768 + (h) * 16384 + sdst), 16, 0, 0); \
    __builtin_amdgcn_global_load_lds((AS1 const void*)(gB + (size_t)((h) * 128 + 64) * KDIM + (kt) * 128), \
        (AS3 void*)(sB + (buf) * 32768 + (h) * 16384 + 8192 + sdst), 16, 0, 0); \
} while (0)

// 16x16x64 fragments: lane l -> row l&15, k-chunk l>>4; rows at 128-B stride.
#define READ_A0(buf) do { \
    _Pragma("unroll") for (int mi = 0; mi < 4; ++mi) \
    _Pragma("unroll") for (int ks = 0; ks < 2; ++ks) \
        aF0[mi][ks] = *(const i32x4*)(sA + (buf) * 32768 + rbA + mi * 2048 + co[ks]); \
} while (0)

#define READ_A1a(buf) do { \
    _Pragma("unroll") for (int mi = 0; mi < 2; ++mi) \
    _Pragma("unroll") for (int ks = 0; ks < 2; ++ks) \
        aF1[mi][ks] = *(const i32x4*)(sA + (buf) * 32768 + rbA + (4 + mi) * 2048 + co[ks]); \
} while (0)

#define READ_A1b(buf) do { \
    _Pragma("unroll") for (int mi = 2; mi < 4; ++mi) \
    _Pragma("unroll") for (int ks = 0; ks < 2; ++ks) \
        aF1[mi][ks] = *(const i32x4*)(sA + (buf) * 32768 + rbA + (4 + mi) * 2048 + co[ks]); \
} while (0)

#define READ_B01(buf) do { \
    _Pragma("unroll") for (int ni = 0; ni < 2; ++ni) \
    _Pragma("unroll") for (int ks = 0; ks < 2; ++ks) \
        bF01[ni][ks] = *(const i32x4*)(sB + (buf) * 32768 + rbB + ni * 2048 + co[ks]); \
} while (0)

#define READ_B23(buf) do { \
    _Pragma("unroll") for (int ni = 0; ni < 2; ++ni) \
    _Pragma("unroll") for (int ks = 0; ks < 2; ++ks) \
        bF23[ni][ks] = *(const i32x4*)(sB + (buf) * 32768 + rbB + (2 + ni) * 2048 + co[ks]); \
} while (0)

// 16 MFMAs per call: 4 mi x 2 nj x 2 ks.  nhofs selects bF01 (0) or bF23 (2).
#define MMA_(AF, accbase, BF, nhofs) do { \
    __builtin_amdgcn_s_setprio(1); \
    _Pragma("unroll") for (int ks = 0; ks < 2; ++ks) \
    _Pragma("unroll") for (int mi = 0; mi < 4; ++mi) \
    _Pragma("unroll") for (int nj = 0; nj < 2; ++nj) \
        acc[(accbase) + mi][(nhofs) + nj] = __builtin_amdgcn_mfma_i32_16x16x64_i8( \
            AF[mi][ks], BF[nj][ks], acc[(accbase) + mi][(nhofs) + nj], 0, 0, 0); \
    __builtin_amdgcn_s_setprio(0); \
} while (0)

__global__ __launch_bounds__(512, 2) void gemm_bt_i8(
        const int8_t* __restrict__ A,    // [M,K] int8
        const int8_t* __restrict__ Bm,   // [N,K] int8
        const float* __restrict__ scales,// [M] = s_m * sw
        const float* __restrict__ bias,  // [N]
        float* __restrict__ C)           // [M,N] fp32
{
    __shared__ __align__(16) int8_t sA[2 * BM * BK];  // 64 KiB
    __shared__ __align__(16) int8_t sB[2 * BN * BK];  // 64 KiB

    const int tid  = threadIdx.x;
    const int wave = tid >> 6;
    const int lane = tid & 63;
    const int wr   = wave >> 2;       // 0..1  (M half)
    const int wc   = wave & 3;        // 0..3  (N quarter)
    const int lr   = lane & 15;       // row within 16-row fragment
    const int lg   = lane >> 4;       // k-group 0..3

    // T1: XCD-aware swizzle over 512 wgs (32 m-tiles x 16 n-tiles); 512%8==0.
    const int orig = blockIdx.y * 16 + blockIdx.x;
    const int nu   = (orig & 7) * 64 + (orig >> 3);
    const int m0   = (nu >> 4) * BM;
    const int n0   = (nu & 15) * BN;

    // ---- staging (linear LDS dest, inverse-swizzled global src) ----
    const int trow = tid >> 3;
    const int slog = (tid & 7) ^ ((tid >> 3) & 7);
    const int8_t* gA = A  + (size_t)(m0 + trow) * KDIM + slog * 16;
    const int8_t* gB = Bm + (size_t)(n0 + trow) * KDIM + slog * 16;
    const int sdst = tid * 16;

    // ---- fragment read addresses ----
    // phys chunk = (ks*4+lg) ^ (lr&7): 16-lane group covers all 8 chunks 2x
    // -> 2-way = free (m136); measured SQ_LDS_BANK_CONFLICT = 0 (R6).
    const int f3 = lr & 7;
    const int rbA = (wr * 128 + lr) * BK;
    const int rbB = (wc * 64  + lr) * BK;
    int co[2];
#pragma unroll
    for (int ks = 0; ks < 2; ++ks) co[ks] = (((ks << 2) | lg) ^ f3) << 4;

    i32x4 acc[8][4];
#pragma unroll
    for (int mi = 0; mi < 8; ++mi)
#pragma unroll
        for (int ni = 0; ni < 4; ++ni)
#pragma unroll
            for (int r = 0; r < 4; ++r) acc[mi][ni][r] = 0;

    i32x4 aF0[4][2];   // rd P3(t-1), used P1,P2(t)
    i32x4 aF1[4][2];   // rd P1,P2(t), used P3,P4(t)
    i32x4 bF01[2][2];  // rd P4(t-1), used P1,P3(t)
    i32x4 bF23[2][2];  // rd P1(t),   used P2,P4(t)

    // ---- prologue: t0 full + t1.A staged; drain t0; pre-read P1(0) operands ----
    STAGE_A(0, 0, 0); STAGE_A(0, 1, 0);
    STAGE_B(0, 0, 0); STAGE_B(0, 1, 0);
    STAGE_A(1, 0, 1); STAGE_A(1, 1, 1);
    WAITV(4);          // t0 (8 loads) landed; A(t1) (4) in flight
    BAR();
    READ_A0(0); READ_B01(0);   // aF0(t0), bF01(t0) for P1; counted lgkm

#pragma unroll 1
    for (int it = 0; it < NKT / 2 - 1; ++it) {     // 15 iters, tiles e=2it, o=e+1 (0..29)
        const int e = 2 * it;
        // ---- tile e (buf0) ----
        READ_B23(0); READ_A1a(0);  MMA_(aF0, 0, bF01, 0);  STAGE_B(1, 0, e + 1);  BAR();
        READ_A1b(0);               MMA_(aF0, 0, bF23, 2);  STAGE_B(1, 1, e + 1);  LGKM0(); WAITV(4); BAR();
        READ_A0(1);                MMA_(aF1, 4, bF01, 0);  STAGE_A(0, 0, e + 2);  WAITV(2); BAR();
        READ_B01(1);               MMA_(aF1, 4, bF23, 2);  STAGE_A(0, 1, e + 2);  BAR();
        // ---- tile o (buf1) ----
        READ_B23(1); READ_A1a(1);  MMA_(aF0, 0, bF01, 0);  STAGE_B(0, 0, e + 2);  BAR();
        READ_A1b(1);               MMA_(aF0, 0, bF23, 2);  STAGE_B(0, 1, e + 2);  LGKM0(); WAITV(4); BAR();
        READ_A0(0);                MMA_(aF1, 4, bF01, 0);  STAGE_A(1, 0, e + 3);  WAITV(2); BAR();
        READ_B01(0);               MMA_(aF1, 4, bF23, 2);  STAGE_A(1, 1, e + 3);  BAR();
    }

    // ---- tail: tile 30 (buf0; stage B31) + tile 31 (buf1; no staging) ----
    READ_B23(0); READ_A1a(0);  MMA_(aF0, 0, bF01, 0);  STAGE_B(1, 0, 31);  BAR();
    READ_A1b(0);               MMA_(aF0, 0, bF23, 2);  STAGE_B(1, 1, 31);  LGKM0(); WAITV(4); BAR();
    READ_A0(1);                MMA_(aF1, 4, bF01, 0);  WAITV(0); BAR();
    READ_B01(1);               MMA_(aF1, 4, bF23, 2);  BAR();
    READ_B23(1); READ_A1a(1);  MMA_(aF0, 0, bF01, 0);  BAR();
    READ_A1b(1);               MMA_(aF0, 0, bF23, 2);
    MMA_(aF1, 4, bF01, 0);
    MMA_(aF1, 4, bF23, 2);

    // ---- epilogue ----
    // C/D 16x16 layout: col = lr, row = lg*4 + r  [m89/m91, dtype-independent]
#pragma unroll
    for (int mi = 0; mi < 8; ++mi) {
        const int row_base = m0 + wr * 128 + mi * 16 + lg * 4;
        float sc[4];
#pragma unroll
        for (int r = 0; r < 4; ++r) sc[r] = scales[row_base + r];
#pragma unroll
        for (int ni = 0; ni < 4; ++ni) {
            const int col = n0 + wc * 64 + ni * 16 + lr;
            const float bc = bias[col];
#pragma unroll
            for (int r = 0; r < 4; ++r)
                C[(size_t)(row_base + r) * NDIM + col] = (float)acc[mi][ni][r] * sc[r] + bc;
        }
    }
}

// ---- correctness fallback if workspace is too small (not expected to run) ----
__global__ void gemm_naive_f32(const float* __restrict__ x, const int* __restrict__ qw,
                               const float* __restrict__ sw, const float* __restrict__ bias,
                               float* __restrict__ out) {
    size_t id = (size_t)blockIdx.x * blockDim.x + threadIdx.x;
    if (id >= (size_t)MDIM * NDIM) return;
    int m = (int)(id / NDIM);
    int n = (int)(id % NDIM);
    const float* xr = x + (size_t)m * KDIM;
    const int*   wr = qw + (size_t)n * KDIM;
    float acc = 0.f;
    for (int k = 0; k < KDIM; k++) acc += xr[k] * (float)wr[k];
    out[id] = acc * (*sw) + bias[n];
}

extern "C" void kernel_launch(void* const* d_in, const int* in_sizes, int n_in,
                              void* d_out, int out_size, void* d_ws, size_t ws_size,
                              hipStream_t stream) {
    const float* x    = (const float*)d_in[0];
    const int*   qw   = (const int*)d_in[1];
    const float* sw   = (const float*)d_in[2];
    const float* bias = (const float*)d_in[3];
    float* out = (float*)d_out;

    const size_t needA = (size_t)MDIM * KDIM;                  // 32 MiB int8
    const size_t needB = (size_t)NDIM * KDIM;                  // 16 MiB int8
    const size_t needS = (size_t)MDIM * sizeof(float);         // 32 KiB scales

    if (ws_size >= needA + needB + needS) {
        int8_t* Aq = (int8_t*)d_ws;
        int8_t* Bq = Aq + needA;
        float*  scales = (float*)(Bq + needB);

        quant_x<<<MDIM, 256, 0, stream>>>(x, sw, Aq, scales);
        const long nw4 = (long)NDIM * KDIM / 4;
        cvt_w<<<(int)(nw4 / 256), 256, 0, stream>>>(qw, Bq);

        dim3 grid(NDIM / BN, MDIM / BM);                       // (16, 32) = 512 blocks
        gemm_bt_i8<<<grid, 512, 0, stream>>>(Aq, Bq, scales, bias, out);
    } else {
        size_t total = (size_t)MDIM * NDIM;
        gemm_naive_f32<<<(total + 255) / 256, 256, 0, stream>>>(x, qw, sw, bias, out);
    }
}